// Round 9
// baseline (43315.695 us; speedup 1.0000x reference)
//
#include <hip/hip_runtime.h>

// ---------------------------------------------------------------------------
// Encoder: B=64, T=2048, D=256, U=256, UEP=64
// R9 = R6 known-pass pipeline + 5 ablation kernels (scan_v0..v4) that
// decompose the 7.5us/step scan cost via rocprof per-dispatch timing.
// ---------------------------------------------------------------------------

typedef _Float16 h2  __attribute__((ext_vector_type(2)));
typedef _Float16 v8h __attribute__((ext_vector_type(8)));

__device__ __forceinline__ float fdot2_(h2 a, h2 b, float c) {
#if __has_builtin(__builtin_amdgcn_fdot2)
  return __builtin_amdgcn_fdot2(a, b, c, false);
#else
  return c + (float)a[0] * (float)b[0] + (float)a[1] * (float)b[1];
#endif
}

template <int I>
__device__ __forceinline__ h2 pr(v8h v) {
  h2 r; r[0] = v[2 * I]; r[1] = v[2 * I + 1]; return r;
}

// Raw barrier: order LDS (lgkmcnt) but leave global loads/stores in flight.
__device__ __forceinline__ void wg_barrier() {
  __builtin_amdgcn_sched_barrier(0);
  asm volatile("s_waitcnt lgkmcnt(0)" ::: "memory");
  __builtin_amdgcn_sched_barrier(0);
  __builtin_amdgcn_s_barrier();
  __builtin_amdgcn_sched_barrier(0);
}

// ---------------------------------------------------------------------------
__global__ __launch_bounds__(256) void prep_kernel(
    const float* __restrict__ W, const float* __restrict__ U,
    const float* __restrict__ W_EP,
    _Float16* __restrict__ wt, _Float16* __restrict__ uzr,
    _Float16* __restrict__ uh, float* __restrict__ wept)
{
  const int blk = blockIdx.x;
  const int k = threadIdx.x;
  if (blk < 768) {
    const int j = blk;
    wt[(size_t)j * 256 + k] = (_Float16)W[(size_t)k * 768 + j];
  } else if (blk < 1280) {
    const int j = blk - 768;
    uzr[(size_t)j * 256 + k] = (_Float16)U[(size_t)k * 768 + j];
  } else if (blk < 1536) {
    const int j = blk - 1280;
    const int p = k >> 3, e = k & 7;
    uh[((size_t)p * 256 + j) * 8 + e] = (_Float16)U[(size_t)k * 768 + 512 + j];
  } else {
    const int j = blk - 1536;
    wept[(size_t)j * 256 + k] = W_EP[(size_t)k * 192 + j];
  }
}

// ---------------------------------------------------------------------------
__global__ __launch_bounds__(256) void ph1_main_kernel(
    const float* __restrict__ x, const _Float16* __restrict__ wt,
    const float* __restrict__ bvec, const float* __restrict__ gam,
    const float* __restrict__ bet, _Float16* __restrict__ s1out)
{
  __shared__ __align__(16) _Float16 xs[16][256];
  __shared__ float sp[16][768];
  const int tid = threadIdx.x;
  const size_t row0 = (size_t)blockIdx.x * 16;

  #pragma unroll
  for (int i = 0; i < 16; ++i)
    xs[i][tid] = (_Float16)x[(row0 + i) * 256 + tid];
  __syncthreads();

  #pragma unroll 1
  for (int cc = 0; cc < 3; ++cc) {
    const int col = cc * 256 + tid;
    const v8h* wp = (const v8h*)(wt + (size_t)col * 256);
    float acc[16];
    #pragma unroll
    for (int r = 0; r < 16; ++r) acc[r] = 0.f;
    #pragma unroll 4
    for (int c = 0; c < 32; ++c) {
      const v8h w8 = wp[c];
      #pragma unroll
      for (int r = 0; r < 16; ++r) {
        const v8h x8 = *(const v8h*)(&xs[r][c * 8]);
        acc[r] = fdot2_(pr<0>(x8), pr<0>(w8), acc[r]);
        acc[r] = fdot2_(pr<1>(x8), pr<1>(w8), acc[r]);
        acc[r] = fdot2_(pr<2>(x8), pr<2>(w8), acc[r]);
        acc[r] = fdot2_(pr<3>(x8), pr<3>(w8), acc[r]);
      }
    }
    const float bb = bvec[col];
    #pragma unroll
    for (int r = 0; r < 16; ++r) sp[r][col] = acc[r] + bb;
  }
  __syncthreads();

  const int w = tid >> 6, lane = tid & 63;
  for (int rr = 0; rr < 4; ++rr) {
    const int r = (w << 2) | rr;
    float vals[12], sum = 0.f, sq = 0.f;
    #pragma unroll
    for (int j = 0; j < 12; ++j) {
      const float v = sp[r][lane + (j << 6)];
      vals[j] = v; sum += v; sq += v * v;
    }
    #pragma unroll
    for (int m = 32; m >= 1; m >>= 1) {
      sum += __shfl_xor(sum, m); sq += __shfl_xor(sq, m);
    }
    const float mean = sum * (1.f / 768.f);
    const float var = sq * (1.f / 768.f) - mean * mean;
    const float inv = 1.f / (sqrtf(var + 1e-5f) + 1e-5f);
    #pragma unroll
    for (int j = 0; j < 12; ++j) {
      const int c = lane + (j << 6);
      s1out[(row0 + r) * 768 + c] =
          (_Float16)(gam[c] * ((vals[j] - mean) * inv) + bet[c]);
    }
  }
}

// ---------------------------------------------------------------------------
__global__ __launch_bounds__(192) void ph1_ep_kernel(
    const float* __restrict__ x, const float* __restrict__ wept,
    const float* __restrict__ bvec, const float* __restrict__ gam,
    const float* __restrict__ bet, void* __restrict__ s1e, const int store64)
{
  __shared__ __align__(16) float xs[16][256];
  __shared__ double sp[16][192];
  const int tid = threadIdx.x;
  const size_t row0 = (size_t)blockIdx.x * 16;

  for (int idx = tid; idx < 4096; idx += 192)
    xs[idx >> 8][idx & 255] = x[row0 * 256 + idx];
  __syncthreads();

  {
    const float4* wp = (const float4*)(wept + (size_t)tid * 256);
    double acc[16];
    #pragma unroll
    for (int r = 0; r < 16; ++r) acc[r] = 0.0;
    #pragma unroll 2
    for (int c = 0; c < 64; ++c) {
      const float4 w4 = wp[c];
      #pragma unroll
      for (int r = 0; r < 16; ++r) {
        const float4 x4 = *(const float4*)(&xs[r][c * 4]);
        acc[r] += (double)x4.x * (double)w4.x;
        acc[r] += (double)x4.y * (double)w4.y;
        acc[r] += (double)x4.z * (double)w4.z;
        acc[r] += (double)x4.w * (double)w4.w;
      }
    }
    const double bb = (double)bvec[tid];
    #pragma unroll
    for (int r = 0; r < 16; ++r) sp[r][tid] = acc[r] + bb;
  }
  __syncthreads();

  const int w = tid >> 6, lane = tid & 63;
  for (int r = w; r < 16; r += 3) {
    double vals[3], sum = 0.0, sq = 0.0;
    #pragma unroll
    for (int j = 0; j < 3; ++j) {
      const double v = sp[r][lane + (j << 6)];
      vals[j] = v; sum += v; sq += v * v;
    }
    #pragma unroll
    for (int m = 32; m >= 1; m >>= 1) {
      sum += __shfl_xor(sum, m); sq += __shfl_xor(sq, m);
    }
    const double mean = sum * (1.0 / 192.0);
    const double var = sq * (1.0 / 192.0) - mean * mean;
    const double den = sqrt(var + 1e-5) + 1e-5;
    #pragma unroll
    for (int j = 0; j < 3; ++j) {
      const int c = lane + (j << 6);
      const double vv = (double)gam[c] * ((vals[j] - mean) / den) + (double)bet[c];
      if (store64) ((double*)s1e)[(row0 + r) * 192 + c] = vv;
      else         ((float*)s1e)[(row0 + r) * 192 + c] = (float)vv;
    }
  }
}

// ---------------------------------------------------------------------------
#define OFF_UH     0
#define OFF_MASK   131072
#define OFF_HEP    139264
#define OFF_ZEE    139776
#define OFF_RHEP   140288
#define OFF_EPZRP  140800
#define OFF_EPHHP  140928
#define OFF_H2     140992
#define OFF_RH     141504
#define OFF_HF     142016
#define OFF_Z      143040
#define OFF_ZRP    144064
#define OFF_HHP    144128
#define OFF_FLAG   144160
#define SCAN_LDS_BYTES 144192

__global__ __launch_bounds__(512, 2) void scan_kernel(
    const _Float16* __restrict__ uzr_g, const _Float16* __restrict__ uh_g,
    const float* __restrict__ U_EP, const _Float16* __restrict__ s1,
    const void* __restrict__ s1e_v, const int s1e64,
    const int* __restrict__ mask,
    const float* __restrict__ gam1, const float* __restrict__ bet1,
    const float* __restrict__ gamep1, const float* __restrict__ betep1,
    const float* __restrict__ W1, const float* __restrict__ b1,
    float* __restrict__ out)
{
  extern __shared__ char sm[];
  const int t = threadIdx.x;
  const int b = blockIdx.x;
  const int w = t >> 6;
  const int je  = t >> 2;
  const int qe  = t & 3;
  const int jeh = (t & 255) >> 2;

  float*  hf    = (float*)(sm + OFF_HF);
  float*  flagp = (float*)(sm + OFF_FLAG);
  double* hepd  = (double*)(sm + OFF_HEP);
  int*    maskl = (int*)(sm + OFF_MASK);

  {
    const v8h* src = (const v8h*)uh_g;
    v8h* dst = (v8h*)(sm + OFF_UH);
    #pragma unroll
    for (int i = 0; i < 16; ++i) dst[i * 512 + t] = src[i * 512 + t];
  }
  #pragma unroll
  for (int i = 0; i < 4; ++i) maskl[i * 512 + t] = mask[((size_t)b << 11) + i * 512 + t];

  float uz[128];
  {
    const float4* up = (const float4*)uzr_g + (size_t)t * 32;
    #pragma unroll
    for (int c = 0; c < 32; ++c) {
      const float4 v = up[c];
      uz[4 * c + 0] = v.x; uz[4 * c + 1] = v.y;
      uz[4 * c + 2] = v.z; uz[4 * c + 3] = v.w;
    }
  }
  #pragma unroll
  for (int i = 0; i < 128; ++i) asm volatile("" : "+v"(uz[i]));

  float uez[16], ueh[16];
  #pragma unroll
  for (int i = 0; i < 16; ++i) uez[i] = U_EP[(size_t)(16 * qe + i) * 192 + je];
  #pragma unroll
  for (int i = 0; i < 16; ++i) ueh[i] = U_EP[(size_t)(16 * qe + i) * 192 + 128 + jeh];

  const float gz = gam1[t],                bz = bet1[t];
  const float gh = gam1[512 + (t & 255)],  bh = bet1[512 + (t & 255)];
  const float gse = gamep1[je],            bse = betep1[je];
  const float ghe = gamep1[128 + jeh],     bhe = betep1[128 + jeh];
  const double w1d = (double)W1[t & 63];
  const double b1d = (double)b1[0];
  const double* dptr = (const double*)s1e_v;
  const float*  fptr = (const float*)s1e_v;

  if (t < 128) { h2 z2; z2[0] = (_Float16)0.f; z2[1] = (_Float16)0.f;
                 ((h2*)(sm + OFF_H2))[t] = z2; }
  if (t < 256) hf[t] = 0.f;
  if (t < 64)  hepd[t] = 0.0;
  if (t < 2)   flagp[t] = 0.f;

  const size_t n0 = (size_t)b << 11;
  float  s1zr_c = (float)s1[n0 * 768 + t];
  float  s1h_c  = (float)s1[n0 * 768 + 512 + (t & 255)];
  double s1ezr_c = s1e64 ? dptr[n0 * 192 + je]
                         : (double)fptr[n0 * 192 + je];
  double s1ehh_c = s1e64 ? dptr[n0 * 192 + 128 + jeh]
                         : (double)fptr[n0 * 192 + 128 + jeh];
  __syncthreads();

  for (int tt = 0; tt < 2048; ++tt) {
    const size_t n = ((size_t)b << 11) | (size_t)tt;
    const float fz = (flagp[tt & 1] > 0.5f) ? 0.f : 1.f;

    if (tt > 0 && t < 256) out[(n - 1) * 256 + t] = hf[t];

    const int ttn = (tt < 2047) ? tt + 1 : 2047;
    const size_t np1 = ((size_t)b << 11) | (size_t)ttn;
    const float  s1zr_n = (float)s1[np1 * 768 + t];
    const float  s1h_n  = (float)s1[np1 * 768 + 512 + (t & 255)];
    const double s1ezr_n = s1e64 ? dptr[np1 * 192 + je]
                                 : (double)fptr[np1 * 192 + je];
    const double s1ehh_n = s1e64 ? dptr[np1 * 192 + 128 + jeh]
                                 : (double)fptr[np1 * 192 + 128 + jeh];

    if (w == 7) {
      double p = hepd[t & 63] * w1d;
      #pragma unroll
      for (int m = 1; m <= 32; m <<= 1) p += __shfl_xor(p, m);
      if (t == 448) {
        const float e = ((p + b1d) > 0.0) ? 1.f : 0.f;
        flagp[(tt + 1) & 1] = e;
        out[(size_t)33554432 + n] = e;
      }
    }

    float d;
    {
      const v8h* hv = (const v8h*)(sm + OFF_H2);
      float a0 = 0.f, a1 = 0.f, a2 = 0.f, a3 = 0.f;
      #pragma unroll
      for (int c = 0; c < 32; ++c) {
        const v8h hc = hv[c];
        a0 = fdot2_(pr<0>(hc), __builtin_bit_cast(h2, uz[4 * c + 0]), a0);
        a1 = fdot2_(pr<1>(hc), __builtin_bit_cast(h2, uz[4 * c + 1]), a1);
        a2 = fdot2_(pr<2>(hc), __builtin_bit_cast(h2, uz[4 * c + 2]), a2);
        a3 = fdot2_(pr<3>(hc), __builtin_bit_cast(h2, uz[4 * c + 3]), a3);
      }
      d = ((a0 + a1) + (a2 + a3)) * fz;
      float s_ = d, q_ = d * d;
      #pragma unroll
      for (int m = 1; m <= 32; m <<= 1) { s_ += __shfl_xor(s_, m); q_ += __shfl_xor(q_, m); }
      if ((t & 63) == 0) ((float2*)(sm + OFF_ZRP))[w] = make_float2(s_, q_);
    }
    double de;
    {
      const double2* hp = (const double2*)(hepd + 16 * qe);
      double acc = 0.0;
      #pragma unroll
      for (int i = 0; i < 8; ++i) {
        const double2 hv2 = hp[i];
        acc += hv2.x * (double)uez[2 * i] + hv2.y * (double)uez[2 * i + 1];
      }
      acc += __shfl_xor(acc, 1); acc += __shfl_xor(acc, 2);
      de = acc;
      double es = de, eq = de * de;
      #pragma unroll
      for (int m = 4; m <= 32; m <<= 1) { es += __shfl_xor(es, m); eq += __shfl_xor(eq, m); }
      if ((t & 63) == 0) ((double2*)(sm + OFF_EPZRP))[w] = make_double2(es, eq);
    }
    wg_barrier();  // B1

    {
      float S = 0.f, Q = 0.f;
      const float4* zp = (const float4*)(sm + OFF_ZRP);
      #pragma unroll
      for (int i = 0; i < 4; ++i) { const float4 v = zp[i]; S += v.x + v.z; Q += v.y + v.w; }
      const float mean = S * (1.f / 512.f);
      const float var = Q * (1.f / 512.f) - mean * mean;
      const float inv = 1.f / (sqrtf(var + 1e-5f) + 1e-5f);
      const float s2v = gz * ((d - mean) * inv) + bz;
      float sv = 0.2f * (s1zr_c + s2v) + 0.5f;
      sv = fminf(fmaxf(sv, 0.f), 1.f);
      if (t < 256) ((float*)(sm + OFF_Z))[t] = sv;
      else {
        const float rhv = sv * (fz * hf[t - 256]);
        ((_Float16*)(sm + OFF_RH))[t - 256] = (_Float16)rhv;
      }
    }
    if ((t & 3) == 0) {
      double S = 0.0, Q = 0.0;
      const double2* ep = (const double2*)(sm + OFF_EPZRP);
      #pragma unroll
      for (int i = 0; i < 8; ++i) { S += ep[i].x; Q += ep[i].y; }
      const double mean = S * (1.0 / 128.0);
      const double var = Q * (1.0 / 128.0) - mean * mean;
      const double den = sqrt(var + 1e-5) + 1e-5;
      const double s2e = (double)gse * ((de - mean) / den) + (double)bse;
      double se = 0.2 * (s1ezr_c + s2e) + 0.5;
      se = fmin(fmax(se, 0.0), 1.0);
      if (je < 64) ((double*)(sm + OFF_ZEE))[je] = se;
      else         ((double*)(sm + OFF_RHEP))[je - 64] = se * hepd[je - 64];
    }
    wg_barrier();  // B2

    float dh = 0.f;
    double deh = 0.0;
    if (t < 256) {
      const v8h* rhv8 = (const v8h*)(sm + OFF_RH);
      const v8h* uhv  = (const v8h*)(sm + OFF_UH);
      float c0 = 0.f, c1 = 0.f, c2 = 0.f, c3 = 0.f;
      #pragma unroll
      for (int p = 0; p < 32; ++p) {
        const v8h rc = rhv8[p];
        const v8h uc = uhv[p * 256 + t];
        c0 = fdot2_(pr<0>(rc), pr<0>(uc), c0);
        c1 = fdot2_(pr<1>(rc), pr<1>(uc), c1);
        c2 = fdot2_(pr<2>(rc), pr<2>(uc), c2);
        c3 = fdot2_(pr<3>(rc), pr<3>(uc), c3);
      }
      dh = (c0 + c1) + (c2 + c3);
      float s_ = dh, q_ = dh * dh;
      #pragma unroll
      for (int m = 1; m <= 32; m <<= 1) { s_ += __shfl_xor(s_, m); q_ += __shfl_xor(q_, m); }
      if ((t & 63) == 0) ((float2*)(sm + OFF_HHP))[w] = make_float2(s_, q_);
    } else {
      const double2* rp = (const double2*)((double*)(sm + OFF_RHEP) + 16 * qe);
      double acc = 0.0;
      #pragma unroll
      for (int i = 0; i < 8; ++i) {
        const double2 rv = rp[i];
        acc += rv.x * (double)ueh[2 * i] + rv.y * (double)ueh[2 * i + 1];
      }
      acc += __shfl_xor(acc, 1); acc += __shfl_xor(acc, 2);
      deh = acc;
      double es = deh, eq = deh * deh;
      #pragma unroll
      for (int m = 4; m <= 32; m <<= 1) { es += __shfl_xor(es, m); eq += __shfl_xor(eq, m); }
      if ((t & 63) == 0) ((double2*)(sm + OFF_EPHHP))[w - 4] = make_double2(es, eq);
    }
    wg_barrier();  // B3

    const int xm = maskl[tt];
    if (t < 256) {
      float S = 0.f, Q = 0.f;
      const float4* hp4 = (const float4*)(sm + OFF_HHP);
      #pragma unroll
      for (int i = 0; i < 2; ++i) { const float4 v = hp4[i]; S += v.x + v.z; Q += v.y + v.w; }
      const float mean = S * (1.f / 256.f);
      const float var = Q * (1.f / 256.f) - mean * mean;
      const float inv = 1.f / (sqrtf(var + 1e-5f) + 1e-5f);
      const float hhv = gh * ((dh - mean) * inv) + bh;
      const float z = ((float*)(sm + OFF_Z))[t];
      const float hzf = fz * hf[t];
      const float hn = z * hzf + (1.f - z) * tanhf(s1h_c + hhv);
      const float hc_ = (xm > 0) ? hn : hzf;
      hf[t] = hc_;
      const float ho = __shfl_xor(hc_, 1);
      if (!(t & 1)) {
        h2 p2; p2[0] = (_Float16)hc_; p2[1] = (_Float16)ho;
        ((h2*)(sm + OFF_H2))[t >> 1] = p2;
      }
    } else if ((t & 3) == 0) {
      double S = 0.0, Q = 0.0;
      const double2* ep = (const double2*)(sm + OFF_EPHHP);
      #pragma unroll
      for (int i = 0; i < 4; ++i) { S += ep[i].x; Q += ep[i].y; }
      const double mean = S * (1.0 / 64.0);
      const double var = Q * (1.0 / 64.0) - mean * mean;
      const double den = sqrt(var + 1e-5) + 1e-5;
      const double hhe = (double)ghe * ((deh - mean) / den) + (double)bhe;
      const double ze = ((double*)(sm + OFF_ZEE))[jeh];
      const double hold = hepd[jeh];
      const double hepn = ze * hold + (1.0 - ze) * tanh(s1ehh_c + hhe);
      hepd[jeh] = (xm > 0) ? hepn : hold;
    }
    wg_barrier();  // B4

    s1zr_c = s1zr_n; s1h_c = s1h_n; s1ezr_c = s1ezr_n; s1ehh_c = s1ehh_n;
  }
  if (t < 256) out[((((size_t)b << 11) | 2047)) * 256 + t] = hf[t];
}

// ===========================================================================
// Ablation kernels. Same grid (64x512), same 144KB LDS, 2048 steps,
// 4 raw barriers/step, flag read each step. Values kept live via LDS side
// effects or never-true guarded stores into workspace scratch (NOT d_out).
// ===========================================================================

// ---- V0: structure floor (flag + 4 barriers) ------------------------------
__global__ __launch_bounds__(512, 2) void scan_v0(float* __restrict__ sink)
{
  extern __shared__ char sm[];
  float* flagp = (float*)(sm + OFF_FLAG);
  const int t = threadIdx.x;
  if (t < 2) flagp[t] = 0.f;
  __syncthreads();
  float acc = 0.f;
  #pragma unroll 1
  for (int tt = 0; tt < 2048; ++tt) {
    const float fz = (flagp[tt & 1] > 0.5f) ? 0.f : 1.f;
    acc += fz;
    wg_barrier(); wg_barrier(); wg_barrier(); wg_barrier();
  }
  if (acc > 1e30f) sink[t] = acc;
}

// ---- V1: + per-step global loads/stores (real addresses) ------------------
__global__ __launch_bounds__(512, 2) void scan_v1(
    const _Float16* __restrict__ s1, const void* __restrict__ s1e_v,
    const int s1e64, const int* __restrict__ mask, float* __restrict__ outs)
{
  extern __shared__ char sm[];
  float* flagp = (float*)(sm + OFF_FLAG);
  int* maskl = (int*)(sm + OFF_MASK);
  const int t = threadIdx.x, b = blockIdx.x;
  const int je = t >> 2, jeh = (t & 255) >> 2;
  #pragma unroll
  for (int i = 0; i < 4; ++i) maskl[i * 512 + t] = mask[((size_t)b << 11) + i * 512 + t];
  if (t < 2) flagp[t] = 0.f;
  const double* dptr = (const double*)s1e_v;
  const float*  fptr = (const float*)s1e_v;
  __syncthreads();
  float accf = 0.f; double accd = 0.0;
  #pragma unroll 1
  for (int tt = 0; tt < 2048; ++tt) {
    const size_t n = ((size_t)b << 11) | (size_t)tt;
    const float fz = (flagp[tt & 1] > 0.5f) ? 0.f : 1.f;
    if (tt > 0 && t < 256) outs[(n - 1) * 256 + t] = accf;
    const int ttn = (tt < 2047) ? tt + 1 : 2047;
    const size_t np1 = ((size_t)b << 11) | (size_t)ttn;
    const float s1zr_n = (float)s1[np1 * 768 + t];
    const float s1h_n  = (float)s1[np1 * 768 + 512 + (t & 255)];
    const double s1ezr_n = s1e64 ? dptr[np1 * 192 + je] : (double)fptr[np1 * 192 + je];
    const double s1ehh_n = s1e64 ? dptr[np1 * 192 + 128 + jeh] : (double)fptr[np1 * 192 + 128 + jeh];
    const int xm = maskl[tt];
    wg_barrier();
    accf += fz + s1zr_n + s1h_n + (float)xm;
    wg_barrier();
    accd += s1ezr_n + s1ehh_n;
    wg_barrier();
    wg_barrier();
  }
  if (accf + (float)accd > 1e30f) outs[t] = accf;
}

// ---- V2: + main-GRU replica (LDS/VALU, 8-reg weights, no spill) -----------
__global__ __launch_bounds__(512, 2) void scan_v2(
    const _Float16* __restrict__ uh_g, const float* __restrict__ gam1,
    const float* __restrict__ bet1, float* __restrict__ sink)
{
  extern __shared__ char sm[];
  const int t = threadIdx.x, w = t >> 6, lane = t & 63;
  float* hf = (float*)(sm + OFF_HF);
  float* flagp = (float*)(sm + OFF_FLAG);
  {
    const v8h* src = (const v8h*)uh_g;
    v8h* dst = (v8h*)(sm + OFF_UH);
    #pragma unroll
    for (int i = 0; i < 16; ++i) dst[i * 512 + t] = src[i * 512 + t];
  }
  const float gz = gam1[t], bz = bet1[t];
  const float gh = gam1[512 + (t & 255)], bh = bet1[512 + (t & 255)];
  h2 wr[8];
  #pragma unroll
  for (int i = 0; i < 8; ++i) {
    wr[i][0] = (_Float16)(0.01f * (float)((t + i) & 15));
    wr[i][1] = (_Float16)(-0.01f * (float)((t + 2 * i) & 15));
  }
  if (t < 128) { h2 z2; z2[0] = (_Float16)0.01f; z2[1] = (_Float16)0.02f;
                 ((h2*)(sm + OFF_H2))[t] = z2; }
  if (t < 256) hf[t] = 0.01f;
  if (t < 2) flagp[t] = 0.f;
  __syncthreads();
  #pragma unroll 1
  for (int tt = 0; tt < 2048; ++tt) {
    const float fz = (flagp[tt & 1] > 0.5f) ? 0.f : 1.f;
    float d_;
    {
      const v8h* hv = (const v8h*)(sm + OFF_H2);
      float a0 = 0.f, a1 = 0.f, a2 = 0.f, a3 = 0.f;
      #pragma unroll
      for (int c = 0; c < 32; ++c) {
        const v8h hc = hv[c];
        a0 = fdot2_(pr<0>(hc), wr[c & 7], a0);
        a1 = fdot2_(pr<1>(hc), wr[(c + 1) & 7], a1);
        a2 = fdot2_(pr<2>(hc), wr[(c + 2) & 7], a2);
        a3 = fdot2_(pr<3>(hc), wr[(c + 3) & 7], a3);
      }
      d_ = ((a0 + a1) + (a2 + a3)) * fz;
      float s_ = d_, q_ = d_ * d_;
      #pragma unroll
      for (int m = 1; m <= 32; m <<= 1) { s_ += __shfl_xor(s_, m); q_ += __shfl_xor(q_, m); }
      if (lane == 0) ((float2*)(sm + OFF_ZRP))[w] = make_float2(s_, q_);
    }
    wg_barrier();
    {
      float S = 0.f, Q = 0.f;
      const float4* zp = (const float4*)(sm + OFF_ZRP);
      #pragma unroll
      for (int i = 0; i < 4; ++i) { const float4 v = zp[i]; S += v.x + v.z; Q += v.y + v.w; }
      const float mean = S * (1.f / 512.f);
      const float var = Q * (1.f / 512.f) - mean * mean;
      const float inv = 1.f / (sqrtf(var + 1e-5f) + 1e-5f);
      const float s2v = gz * ((d_ - mean) * inv) + bz;
      float sv = 0.2f * (0.1f + s2v) + 0.5f;
      sv = fminf(fmaxf(sv, 0.f), 1.f);
      if (t < 256) ((float*)(sm + OFF_Z))[t] = sv;
      else {
        const float rhv = sv * (fz * hf[t - 256]);
        ((_Float16*)(sm + OFF_RH))[t - 256] = (_Float16)rhv;
      }
    }
    wg_barrier();
    float dh = 0.f;
    if (t < 256) {
      const v8h* rhv8 = (const v8h*)(sm + OFF_RH);
      const v8h* uhv  = (const v8h*)(sm + OFF_UH);
      float c0 = 0.f, c1 = 0.f, c2 = 0.f, c3 = 0.f;
      #pragma unroll
      for (int p = 0; p < 32; ++p) {
        const v8h rc = rhv8[p];
        const v8h uc = uhv[p * 256 + t];
        c0 = fdot2_(pr<0>(rc), pr<0>(uc), c0);
        c1 = fdot2_(pr<1>(rc), pr<1>(uc), c1);
        c2 = fdot2_(pr<2>(rc), pr<2>(uc), c2);
        c3 = fdot2_(pr<3>(rc), pr<3>(uc), c3);
      }
      dh = (c0 + c1) + (c2 + c3);
      float s_ = dh, q_ = dh * dh;
      #pragma unroll
      for (int m = 1; m <= 32; m <<= 1) { s_ += __shfl_xor(s_, m); q_ += __shfl_xor(q_, m); }
      if (lane == 0) ((float2*)(sm + OFF_HHP))[w] = make_float2(s_, q_);
    }
    wg_barrier();
    if (t < 256) {
      float S = 0.f, Q = 0.f;
      const float4* hp4 = (const float4*)(sm + OFF_HHP);
      #pragma unroll
      for (int i = 0; i < 2; ++i) { const float4 v = hp4[i]; S += v.x + v.z; Q += v.y + v.w; }
      const float mean = S * (1.f / 256.f);
      const float var = Q * (1.f / 256.f) - mean * mean;
      const float inv = 1.f / (sqrtf(var + 1e-5f) + 1e-5f);
      const float hhv = gh * ((dh - mean) * inv) + bh;
      const float z = ((float*)(sm + OFF_Z))[t];
      const float hzf = fz * hf[t];
      const float hn = z * hzf + (1.f - z) * tanhf(0.1f + hhv);
      hf[t] = hn;
      const float ho = __shfl_xor(hn, 1);
      if (!(t & 1)) { h2 p2; p2[0] = (_Float16)hn; p2[1] = (_Float16)ho;
                      ((h2*)(sm + OFF_H2))[t >> 1] = p2; }
    }
    wg_barrier();
  }
  if (hf[t & 255] > 1e30f) sink[t] = 1.f;
}

// ---- V3: + EP fp64 replica (incl. is_end/flag chain) ----------------------
__global__ __launch_bounds__(512, 2) void scan_v3(
    const float* __restrict__ U_EP, const float* __restrict__ gamep1,
    const float* __restrict__ betep1, const float* __restrict__ W1,
    const float* __restrict__ b1, float* __restrict__ sink)
{
  extern __shared__ char sm[];
  const int t = threadIdx.x, w = t >> 6, lane = t & 63;
  const int je = t >> 2, qe = t & 3, jeh = (t & 255) >> 2;
  double* hepd = (double*)(sm + OFF_HEP);
  float* flagp = (float*)(sm + OFF_FLAG);
  float uez[16], ueh[16];
  #pragma unroll
  for (int i = 0; i < 16; ++i) uez[i] = U_EP[(size_t)(16 * qe + i) * 192 + je];
  #pragma unroll
  for (int i = 0; i < 16; ++i) ueh[i] = U_EP[(size_t)(16 * qe + i) * 192 + 128 + jeh];
  const float gse = gamep1[je], bse = betep1[je];
  const float ghe = gamep1[128 + jeh], bhe = betep1[128 + jeh];
  const double w1d = (double)W1[lane];
  const double b1d = (double)b1[0];
  if (t < 64) hepd[t] = 0.01;
  if (t < 2) flagp[t] = 0.f;
  __syncthreads();
  #pragma unroll 1
  for (int tt = 0; tt < 2048; ++tt) {
    const float fz = (flagp[tt & 1] > 0.5f) ? 0.f : 1.f;
    double de;
    {
      const double2* hp = (const double2*)(hepd + 16 * qe);
      double acc = 0.0;
      #pragma unroll
      for (int i = 0; i < 8; ++i) {
        const double2 hv2 = hp[i];
        acc += hv2.x * (double)uez[2 * i] + hv2.y * (double)uez[2 * i + 1];
      }
      acc += __shfl_xor(acc, 1); acc += __shfl_xor(acc, 2);
      de = acc;
      double es = de, eq = de * de;
      #pragma unroll
      for (int m = 4; m <= 32; m <<= 1) { es += __shfl_xor(es, m); eq += __shfl_xor(eq, m); }
      if (lane == 0) ((double2*)(sm + OFF_EPZRP))[w] = make_double2(es, eq);
    }
    if (w == 7) {
      double p = hepd[lane] * w1d;
      #pragma unroll
      for (int m = 1; m <= 32; m <<= 1) p += __shfl_xor(p, m);
      if (t == 448) flagp[(tt + 1) & 1] = ((p + b1d) > 1e30) ? 1.f : 0.f;
    }
    wg_barrier();
    if ((t & 3) == 0) {
      double S = 0.0, Q = 0.0;
      const double2* ep = (const double2*)(sm + OFF_EPZRP);
      #pragma unroll
      for (int i = 0; i < 8; ++i) { S += ep[i].x; Q += ep[i].y; }
      const double mean = S * (1.0 / 128.0);
      const double var = Q * (1.0 / 128.0) - mean * mean;
      const double den = sqrt(var + 1e-5) + 1e-5;
      const double s2e = (double)gse * ((de - mean) / den) + (double)bse;
      double se = 0.2 * (0.01 + s2e) + 0.5;
      se = fmin(fmax(se, 0.0), 1.0);
      if (je < 64) ((double*)(sm + OFF_ZEE))[je] = se;
      else         ((double*)(sm + OFF_RHEP))[je - 64] = se * hepd[je - 64];
    }
    wg_barrier();
    double deh = 0.0;
    if (t >= 256) {
      const double2* rp = (const double2*)((double*)(sm + OFF_RHEP) + 16 * qe);
      double acc = 0.0;
      #pragma unroll
      for (int i = 0; i < 8; ++i) {
        const double2 rv = rp[i];
        acc += rv.x * (double)ueh[2 * i] + rv.y * (double)ueh[2 * i + 1];
      }
      acc += __shfl_xor(acc, 1); acc += __shfl_xor(acc, 2);
      deh = acc;
      double es = deh, eq = deh * deh;
      #pragma unroll
      for (int m = 4; m <= 32; m <<= 1) { es += __shfl_xor(es, m); eq += __shfl_xor(eq, m); }
      if (lane == 0) ((double2*)(sm + OFF_EPHHP))[w - 4] = make_double2(es, eq);
    }
    wg_barrier();
    if (t >= 256 && (t & 3) == 0) {
      double S = 0.0, Q = 0.0;
      const double2* ep = (const double2*)(sm + OFF_EPHHP);
      #pragma unroll
      for (int i = 0; i < 4; ++i) { S += ep[i].x; Q += ep[i].y; }
      const double mean = S * (1.0 / 64.0);
      const double var = Q * (1.0 / 64.0) - mean * mean;
      const double den = sqrt(var + 1e-5) + 1e-5;
      const double hhe = (double)ghe * ((deh - mean) / den) + (double)bhe;
      const double ze = ((double*)(sm + OFF_ZEE))[jeh];
      const double hold = hepd[jeh];
      const double hepn = ze * hold + (1.0 - ze) * tanh(0.01 + hhe);
      hepd[jeh] = (fz > -1.f) ? hepn : hold;
    }
    wg_barrier();
  }
  if (hepd[t & 63] > 1e30) sink[t] = 1.f;
}

// ---- V4: + true Uzr L2 streaming (LICM defeated via ptr-obscure asm) ------
__global__ __launch_bounds__(512, 2) void scan_v4(
    const _Float16* __restrict__ uzr_g, float* __restrict__ sink)
{
  extern __shared__ char sm[];
  float* flagp = (float*)(sm + OFF_FLAG);
  const int t = threadIdx.x;
  if (t < 2) flagp[t] = 0.f;
  __syncthreads();
  const v8h* up = (const v8h*)uzr_g + (size_t)t * 32;
  float acc = 0.f;
  #pragma unroll 1
  for (int tt = 0; tt < 2048; ++tt) {
    const float fz = (flagp[tt & 1] > 0.5f) ? 0.f : 1.f;
    const v8h* upt = up;
    asm volatile("" : "+v"(upt));      // per-iteration: loads can't be hoisted
    v8h wz[16];
    #pragma unroll
    for (int c = 0; c < 16; ++c) wz[c] = upt[c];
    #pragma unroll
    for (int c = 0; c < 16; ++c) acc += (float)wz[c][0];
    wg_barrier();
    #pragma unroll
    for (int c = 0; c < 16; ++c) wz[c] = upt[16 + c];
    #pragma unroll
    for (int c = 0; c < 16; ++c) acc += (float)wz[c][1];
    wg_barrier();
    acc += fz;
    wg_barrier();
    wg_barrier();
  }
  if (acc > 1e30f) sink[t] = acc;
}

// ---------------------------------------------------------------------------
extern "C" void kernel_launch(void* const* d_in, const int* in_sizes, int n_in,
                              void* d_out, int out_size, void* d_ws, size_t ws_size,
                              hipStream_t stream)
{
  (void)in_sizes; (void)n_in; (void)out_size;
  const float* x       = (const float*)d_in[0];
  const int*   mask    = (const int*)d_in[1];
  const float* W       = (const float*)d_in[2];
  const float* U       = (const float*)d_in[3];
  const float* bvec    = (const float*)d_in[4];
  const float* gammas  = (const float*)d_in[5];
  const float* betas   = (const float*)d_in[6];
  const float* W_EP    = (const float*)d_in[7];
  const float* U_EP    = (const float*)d_in[8];
  const float* b_EP    = (const float*)d_in[9];
  const float* gammasE = (const float*)d_in[10];
  const float* betasE  = (const float*)d_in[11];
  const float* W1_EP   = (const float*)d_in[12];
  const float* b1_EP   = (const float*)d_in[13];
  float* out = (float*)d_out;

  const size_t NR = 131072;
  const size_t S1_SZ    = NR * 768 * 2;
  const size_t S1E64_SZ = NR * 192 * 8;
  const size_t S1E32_SZ = NR * 192 * 4;
  const size_t WSMALL = 262144 + 131072 + 393216 + 196608;
  const int s1e64 = (ws_size >= S1_SZ + S1E64_SZ + WSMALL) ? 1 : 0;
  const size_t S1E_SZ = s1e64 ? S1E64_SZ : S1E32_SZ;
  if (ws_size < S1_SZ + S1E32_SZ + WSMALL) return;

  char* ws = (char*)d_ws;
  size_t off = 0;
  void* s1e      = (void*)(ws + off);      off += S1E_SZ;
  _Float16* s1   = (_Float16*)(ws + off);  off += S1_SZ;
  _Float16* uzr  = (_Float16*)(ws + off);  off += 262144;
  _Float16* uh   = (_Float16*)(ws + off);  off += 131072;
  _Float16* wt   = (_Float16*)(ws + off);  off += 393216;
  float* wept    = (float*)(ws + off);     off += 196608;

  prep_kernel<<<dim3(1728), dim3(256), 0, stream>>>(
      W, U, W_EP, wt, uzr, uh, wept);
  ph1_main_kernel<<<dim3(8192), dim3(256), 0, stream>>>(
      x, wt, bvec, gammas, betas, s1);
  ph1_ep_kernel<<<dim3(8192), dim3(192), 0, stream>>>(
      x, wept, b_EP, gammasE, betasE, s1e, s1e64);

  hipFuncSetAttribute(reinterpret_cast<const void*>(scan_kernel),
                      hipFuncAttributeMaxDynamicSharedMemorySize, SCAN_LDS_BYTES);
  scan_kernel<<<dim3(64), dim3(512), SCAN_LDS_BYTES, stream>>>(
      uzr, uh, U_EP, s1, (const void*)s1e, s1e64, mask,
      gammas + 768, betas + 768, gammasE + 192, betasE + 192,
      W1_EP, b1_EP, out);

  // ---- ablation dispatches (write only into workspace scratch) ----
  float* sink = (float*)wt;            // wt consumed by ph1_main above; safe
  float* outs = (float*)s1;            // s1 consumed by scan_kernel above; safe

  hipFuncSetAttribute(reinterpret_cast<const void*>(scan_v0),
                      hipFuncAttributeMaxDynamicSharedMemorySize, SCAN_LDS_BYTES);
  scan_v0<<<dim3(64), dim3(512), SCAN_LDS_BYTES, stream>>>(sink);

  hipFuncSetAttribute(reinterpret_cast<const void*>(scan_v1),
                      hipFuncAttributeMaxDynamicSharedMemorySize, SCAN_LDS_BYTES);
  scan_v1<<<dim3(64), dim3(512), SCAN_LDS_BYTES, stream>>>(
      s1, (const void*)s1e, s1e64, mask, outs);

  hipFuncSetAttribute(reinterpret_cast<const void*>(scan_v2),
                      hipFuncAttributeMaxDynamicSharedMemorySize, SCAN_LDS_BYTES);
  scan_v2<<<dim3(64), dim3(512), SCAN_LDS_BYTES, stream>>>(
      uh, gammas + 768, betas + 768, sink);

  hipFuncSetAttribute(reinterpret_cast<const void*>(scan_v3),
                      hipFuncAttributeMaxDynamicSharedMemorySize, SCAN_LDS_BYTES);
  scan_v3<<<dim3(64), dim3(512), SCAN_LDS_BYTES, stream>>>(
      U_EP, gammasE + 192, betasE + 192, W1_EP, b1_EP, sink);

  hipFuncSetAttribute(reinterpret_cast<const void*>(scan_v4),
                      hipFuncAttributeMaxDynamicSharedMemorySize, SCAN_LDS_BYTES);
  scan_v4<<<dim3(64), dim3(512), SCAN_LDS_BYTES, stream>>>(uzr, sink);
}

// Round 10
// 17545.689 us; speedup vs baseline: 2.4687x; 2.4687x over previous
//
#include <hip/hip_runtime.h>

// ---------------------------------------------------------------------------
// Encoder: B=64, T=2048, D=256, U=256, UEP=64
//  Phase 1a: s1  = ln(x @ W + b)    -> f16   [131072][768]
//  Phase 1b: s1e = ln(x @ W_EP + b) -> f64   [131072][192]  (exact fp64)
//  Phase 2 : 64 WGs x 512 thr, 2048 steps, 4 RAW barriers/step.
//    R10 KEY CHANGE: Uzr column (128 words) lives in 128 AGPRs via inline-asm
//    v_accvgpr_write_b32 / v_accvgpr_read_b32. The VGPR allocator insists on
//    a 128-VGPR budget (R3-R8: weights spilled to scratch -> ~256KB/step L2
//    re-reads, latency-bound ~5us/step). AGPRs sit outside that budget in the
//    unified 256-reg/wave file (128 VGPR + 128 AGPR = exact fit), so weights
//    become truly CU-resident with zero per-step memory traffic.
//    Uh: LDS chunk-major pages (conflict-free unique reads).
//    EP GRU + is_end: fp64 (discrete round(sigmoid) must match reference).
// ---------------------------------------------------------------------------

typedef _Float16 h2  __attribute__((ext_vector_type(2)));
typedef _Float16 v8h __attribute__((ext_vector_type(8)));

__device__ __forceinline__ float fdot2_(h2 a, h2 b, float c) {
#if __has_builtin(__builtin_amdgcn_fdot2)
  return __builtin_amdgcn_fdot2(a, b, c, false);
#else
  return c + (float)a[0] * (float)b[0] + (float)a[1] * (float)b[1];
#endif
}

template <int I>
__device__ __forceinline__ h2 pr(v8h v) {
  h2 r; r[0] = v[2 * I]; r[1] = v[2 * I + 1]; return r;
}

// Raw barrier: order LDS (lgkmcnt) but leave global loads/stores in flight.
__device__ __forceinline__ void wg_barrier() {
  __builtin_amdgcn_sched_barrier(0);
  asm volatile("s_waitcnt lgkmcnt(0)" ::: "memory");
  __builtin_amdgcn_sched_barrier(0);
  __builtin_amdgcn_s_barrier();
  __builtin_amdgcn_sched_barrier(0);
}

// ---------------------------------------------------------------------------
// prep: weight transposes / conversions.
// blocks: [0,768) wt | [768,1280) uzr | [1280,1536) uh chunk-major | [1536,1728) wept
// ---------------------------------------------------------------------------
__global__ __launch_bounds__(256) void prep_kernel(
    const float* __restrict__ W, const float* __restrict__ U,
    const float* __restrict__ W_EP,
    _Float16* __restrict__ wt, _Float16* __restrict__ uzr,
    _Float16* __restrict__ uh, float* __restrict__ wept)
{
  const int blk = blockIdx.x;
  const int k = threadIdx.x;
  if (blk < 768) {                       // wt[j][k] = W[k][j]  (f16)
    const int j = blk;
    wt[(size_t)j * 256 + k] = (_Float16)W[(size_t)k * 768 + j];
  } else if (blk < 1280) {               // uzr[j][k] = U[k][j], j<512 (f16)
    const int j = blk - 768;
    uzr[(size_t)j * 256 + k] = (_Float16)U[(size_t)k * 768 + j];
  } else if (blk < 1536) {               // uh chunk-major: page p=k>>3, elem k&7
    const int j = blk - 1280;            // col 0..255
    const int p = k >> 3, e = k & 7;
    uh[((size_t)p * 256 + j) * 8 + e] = (_Float16)U[(size_t)k * 768 + 512 + j];
  } else {                               // wept[j][k] = W_EP[k][j] (f32)
    const int j = blk - 1536;
    wept[(size_t)j * 256 + k] = W_EP[(size_t)k * 192 + j];
  }
}

// ---------------------------------------------------------------------------
// Phase 1a: main s1 = ln(x@W + b, gammas[0], betas[0]) stored f16.
// ---------------------------------------------------------------------------
__global__ __launch_bounds__(256) void ph1_main_kernel(
    const float* __restrict__ x, const _Float16* __restrict__ wt,
    const float* __restrict__ bvec, const float* __restrict__ gam,
    const float* __restrict__ bet, _Float16* __restrict__ s1out)
{
  __shared__ __align__(16) _Float16 xs[16][256];   // 8 KB
  __shared__ float sp[16][768];                    // 48 KB
  const int tid = threadIdx.x;
  const size_t row0 = (size_t)blockIdx.x * 16;

  #pragma unroll
  for (int i = 0; i < 16; ++i)
    xs[i][tid] = (_Float16)x[(row0 + i) * 256 + tid];
  __syncthreads();

  #pragma unroll 1
  for (int cc = 0; cc < 3; ++cc) {
    const int col = cc * 256 + tid;
    const v8h* wp = (const v8h*)(wt + (size_t)col * 256);
    float acc[16];
    #pragma unroll
    for (int r = 0; r < 16; ++r) acc[r] = 0.f;
    #pragma unroll 4
    for (int c = 0; c < 32; ++c) {
      const v8h w8 = wp[c];
      #pragma unroll
      for (int r = 0; r < 16; ++r) {
        const v8h x8 = *(const v8h*)(&xs[r][c * 8]);
        acc[r] = fdot2_(pr<0>(x8), pr<0>(w8), acc[r]);
        acc[r] = fdot2_(pr<1>(x8), pr<1>(w8), acc[r]);
        acc[r] = fdot2_(pr<2>(x8), pr<2>(w8), acc[r]);
        acc[r] = fdot2_(pr<3>(x8), pr<3>(w8), acc[r]);
      }
    }
    const float bb = bvec[col];
    #pragma unroll
    for (int r = 0; r < 16; ++r) sp[r][col] = acc[r] + bb;
  }
  __syncthreads();

  const int w = tid >> 6, lane = tid & 63;
  for (int rr = 0; rr < 4; ++rr) {
    const int r = (w << 2) | rr;
    float vals[12], sum = 0.f, sq = 0.f;
    #pragma unroll
    for (int j = 0; j < 12; ++j) {
      const float v = sp[r][lane + (j << 6)];
      vals[j] = v; sum += v; sq += v * v;
    }
    #pragma unroll
    for (int m = 32; m >= 1; m >>= 1) {
      sum += __shfl_xor(sum, m); sq += __shfl_xor(sq, m);
    }
    const float mean = sum * (1.f / 768.f);
    const float var = sq * (1.f / 768.f) - mean * mean;
    const float inv = 1.f / (sqrtf(var + 1e-5f) + 1e-5f);
    #pragma unroll
    for (int j = 0; j < 12; ++j) {
      const int c = lane + (j << 6);
      s1out[(row0 + r) * 768 + c] =
          (_Float16)(gam[c] * ((vals[j] - mean) * inv) + bet[c]);
    }
  }
}

// ---------------------------------------------------------------------------
// Phase 1b: EP s1e = ln(x@W_EP + b_EP) in exact fp64, stored f64 (or f32).
// ---------------------------------------------------------------------------
__global__ __launch_bounds__(192) void ph1_ep_kernel(
    const float* __restrict__ x, const float* __restrict__ wept,
    const float* __restrict__ bvec, const float* __restrict__ gam,
    const float* __restrict__ bet, void* __restrict__ s1e, const int store64)
{
  __shared__ __align__(16) float xs[16][256];   // 16 KB
  __shared__ double sp[16][192];                // 24 KB
  const int tid = threadIdx.x;
  const size_t row0 = (size_t)blockIdx.x * 16;

  for (int idx = tid; idx < 4096; idx += 192)
    xs[idx >> 8][idx & 255] = x[row0 * 256 + idx];
  __syncthreads();

  {
    const float4* wp = (const float4*)(wept + (size_t)tid * 256);
    double acc[16];
    #pragma unroll
    for (int r = 0; r < 16; ++r) acc[r] = 0.0;
    #pragma unroll 2
    for (int c = 0; c < 64; ++c) {
      const float4 w4 = wp[c];
      #pragma unroll
      for (int r = 0; r < 16; ++r) {
        const float4 x4 = *(const float4*)(&xs[r][c * 4]);
        acc[r] += (double)x4.x * (double)w4.x;
        acc[r] += (double)x4.y * (double)w4.y;
        acc[r] += (double)x4.z * (double)w4.z;
        acc[r] += (double)x4.w * (double)w4.w;
      }
    }
    const double bb = (double)bvec[tid];
    #pragma unroll
    for (int r = 0; r < 16; ++r) sp[r][tid] = acc[r] + bb;
  }
  __syncthreads();

  const int w = tid >> 6, lane = tid & 63;
  for (int r = w; r < 16; r += 3) {
    double vals[3], sum = 0.0, sq = 0.0;
    #pragma unroll
    for (int j = 0; j < 3; ++j) {
      const double v = sp[r][lane + (j << 6)];
      vals[j] = v; sum += v; sq += v * v;
    }
    #pragma unroll
    for (int m = 32; m >= 1; m >>= 1) {
      sum += __shfl_xor(sum, m); sq += __shfl_xor(sq, m);
    }
    const double mean = sum * (1.0 / 192.0);
    const double var = sq * (1.0 / 192.0) - mean * mean;
    const double den = sqrt(var + 1e-5) + 1e-5;
    #pragma unroll
    for (int j = 0; j < 3; ++j) {
      const int c = lane + (j << 6);
      const double vv = (double)gam[c] * ((vals[j] - mean) / den) + (double)bet[c];
      if (store64) ((double*)s1e)[(row0 + r) * 192 + c] = vv;
      else         ((float*)s1e)[(row0 + r) * 192 + c] = (float)vv;
    }
  }
}

// ---------------------------------------------------------------------------
// Phase 2 LDS map (dynamic, 144192 B)
// ---------------------------------------------------------------------------
#define OFF_UH     0        /* 131072  f16 Uh chunk-major [32 pages][256 cols][8] */
#define OFF_MASK   131072   /* 8192    int mask row                               */
#define OFF_HEP    139264   /* 512     f64 hep[64]                                */
#define OFF_ZEE    139776   /* 512     f64 ze[64]                                 */
#define OFF_RHEP   140288   /* 512     f64 rhep[64]                               */
#define OFF_EPZRP  140800   /* 128     double2 epzrP[8]                           */
#define OFF_EPHHP  140928   /* 64      double2 ephhP[4]                           */
#define OFF_H2     140992   /* 512     f16 h packed h2[128]                       */
#define OFF_RH     141504   /* 512     f16 rh packed                              */
#define OFF_HF     142016   /* 1024    f32 h[256]                                 */
#define OFF_Z      143040   /* 1024    f32 z[256]                                 */
#define OFF_ZRP    144064   /* 64      float2 zrP[8]                              */
#define OFF_HHP    144128   /* 32      float2 hhP[4]                              */
#define OFF_FLAG   144160   /* 8       f32 flag[2]                                */
#define SCAN_LDS_BYTES 144192

__global__ __launch_bounds__(512, 2) void scan_kernel(
    const _Float16* __restrict__ uzr_g, const _Float16* __restrict__ uh_g,
    const float* __restrict__ U_EP, const _Float16* __restrict__ s1,
    const void* __restrict__ s1e_v, const int s1e64,
    const int* __restrict__ mask,
    const float* __restrict__ gam1, const float* __restrict__ bet1,
    const float* __restrict__ gamep1, const float* __restrict__ betep1,
    const float* __restrict__ W1, const float* __restrict__ b1,
    float* __restrict__ out)
{
  extern __shared__ char sm[];
  const int t = threadIdx.x;
  const int b = blockIdx.x;
  const int w = t >> 6;
  const int je  = t >> 2;            // EP-zr col 0..127
  const int qe  = t & 3;             // EP K-slice
  const int jeh = (t & 255) >> 2;    // EP-hh col 0..63

  float*  hf    = (float*)(sm + OFF_HF);
  float*  flagp = (float*)(sm + OFF_FLAG);
  double* hepd  = (double*)(sm + OFF_HEP);
  int*    maskl = (int*)(sm + OFF_MASK);

  // ---- stage Uh (linear copy; layout already chunk-major) ----
  {
    const v8h* src = (const v8h*)uh_g;
    v8h* dst = (v8h*)(sm + OFF_UH);
    #pragma unroll
    for (int i = 0; i < 16; ++i) dst[i * 512 + t] = src[i * 512 + t];
  }
  // ---- stage mask row ----
  #pragma unroll
  for (int i = 0; i < 4; ++i) maskl[i * 512 + t] = mask[((size_t)b << 11) + i * 512 + t];

  // ---- Uzr full column t -> 128 AGPRs (outside the 128-VGPR budget) ----
  float az[128];
  {
    const float4* up = (const float4*)uzr_g + (size_t)t * 32;
    #pragma unroll
    for (int c = 0; c < 32; ++c) {
      const float4 v = up[c];
      asm volatile("v_accvgpr_write_b32 %0, %1" : "=a"(az[4 * c + 0]) : "v"(v.x));
      asm volatile("v_accvgpr_write_b32 %0, %1" : "=a"(az[4 * c + 1]) : "v"(v.y));
      asm volatile("v_accvgpr_write_b32 %0, %1" : "=a"(az[4 * c + 2]) : "v"(v.z));
      asm volatile("v_accvgpr_write_b32 %0, %1" : "=a"(az[4 * c + 3]) : "v"(v.w));
    }
  }

  // ---- EP weights (f32 regs) ----
  float uez[16], ueh[16];
  #pragma unroll
  for (int i = 0; i < 16; ++i) uez[i] = U_EP[(size_t)(16 * qe + i) * 192 + je];
  #pragma unroll
  for (int i = 0; i < 16; ++i) ueh[i] = U_EP[(size_t)(16 * qe + i) * 192 + 128 + jeh];

  // ---- constants ----
  const float gz = gam1[t],                bz = bet1[t];
  const float gh = gam1[512 + (t & 255)],  bh = bet1[512 + (t & 255)];
  const float gse = gamep1[je],            bse = betep1[je];
  const float ghe = gamep1[128 + jeh],     bhe = betep1[128 + jeh];
  const double w1d = (double)W1[t & 63];
  const double b1d = (double)b1[0];
  const double* dptr = (const double*)s1e_v;
  const float*  fptr = (const float*)s1e_v;

  // ---- init state ----
  if (t < 128) { h2 z2; z2[0] = (_Float16)0.f; z2[1] = (_Float16)0.f;
                 ((h2*)(sm + OFF_H2))[t] = z2; }
  if (t < 256) hf[t] = 0.f;
  if (t < 64)  hepd[t] = 0.0;
  if (t < 2)   flagp[t] = 0.f;

  // ---- prefetch step 0 ----
  const size_t n0 = (size_t)b << 11;
  float  s1zr_c = (float)s1[n0 * 768 + t];
  float  s1h_c  = (float)s1[n0 * 768 + 512 + (t & 255)];
  double s1ezr_c = s1e64 ? dptr[n0 * 192 + je]
                         : (double)fptr[n0 * 192 + je];
  double s1ehh_c = s1e64 ? dptr[n0 * 192 + 128 + jeh]
                         : (double)fptr[n0 * 192 + 128 + jeh];
  __syncthreads();

  for (int tt = 0; tt < 2048; ++tt) {
    const size_t n = ((size_t)b << 11) | (size_t)tt;
    const float fz = (flagp[tt & 1] > 0.5f) ? 0.f : 1.f;

    // ---- Seg1: deferred h-write | prefetch t+1 | is_end | zr dot | EP-zr dot
    if (tt > 0 && t < 256) out[(n - 1) * 256 + t] = hf[t];

    const int ttn = (tt < 2047) ? tt + 1 : 2047;
    const size_t np1 = ((size_t)b << 11) | (size_t)ttn;
    const float  s1zr_n = (float)s1[np1 * 768 + t];
    const float  s1h_n  = (float)s1[np1 * 768 + 512 + (t & 255)];
    const double s1ezr_n = s1e64 ? dptr[np1 * 192 + je]
                                 : (double)fptr[np1 * 192 + je];
    const double s1ehh_n = s1e64 ? dptr[np1 * 192 + 128 + jeh]
                                 : (double)fptr[np1 * 192 + 128 + jeh];

    if (w == 7) {                       // is_end from hep (pre-update)
      double p = hepd[t & 63] * w1d;
      #pragma unroll
      for (int m = 1; m <= 32; m <<= 1) p += __shfl_xor(p, m);
      if (t == 448) {
        const float e = ((p + b1d) > 0.0) ? 1.f : 0.f;
        flagp[(tt + 1) & 1] = e;
        out[(size_t)33554432 + n] = e;
      }
    }

    float d;                            // zr dot: full-K column t (AGPR weights)
    {
      const v8h* hv = (const v8h*)(sm + OFF_H2);
      float a0 = 0.f, a1 = 0.f, a2 = 0.f, a3 = 0.f;
      #pragma unroll
      for (int c = 0; c < 32; ++c) {
        const v8h hc = hv[c];
        float w0, w1, w2, w3;
        asm volatile("v_accvgpr_read_b32 %0, %1" : "=v"(w0) : "a"(az[4 * c + 0]));
        asm volatile("v_accvgpr_read_b32 %0, %1" : "=v"(w1) : "a"(az[4 * c + 1]));
        asm volatile("v_accvgpr_read_b32 %0, %1" : "=v"(w2) : "a"(az[4 * c + 2]));
        asm volatile("v_accvgpr_read_b32 %0, %1" : "=v"(w3) : "a"(az[4 * c + 3]));
        a0 = fdot2_(pr<0>(hc), __builtin_bit_cast(h2, w0), a0);
        a1 = fdot2_(pr<1>(hc), __builtin_bit_cast(h2, w1), a1);
        a2 = fdot2_(pr<2>(hc), __builtin_bit_cast(h2, w2), a2);
        a3 = fdot2_(pr<3>(hc), __builtin_bit_cast(h2, w3), a3);
      }
      d = ((a0 + a1) + (a2 + a3)) * fz;
      float s_ = d, q_ = d * d;
      #pragma unroll
      for (int m = 1; m <= 32; m <<= 1) { s_ += __shfl_xor(s_, m); q_ += __shfl_xor(q_, m); }
      if ((t & 63) == 0) ((float2*)(sm + OFF_ZRP))[w] = make_float2(s_, q_);
    }
    double de;                          // EP-zr dot: col je, K-slice qe
    {
      const double2* hp = (const double2*)(hepd + 16 * qe);
      double acc = 0.0;
      #pragma unroll
      for (int i = 0; i < 8; ++i) {
        const double2 hv2 = hp[i];
        acc += hv2.x * (double)uez[2 * i] + hv2.y * (double)uez[2 * i + 1];
      }
      acc += __shfl_xor(acc, 1); acc += __shfl_xor(acc, 2);
      de = acc;
      double es = de, eq = de * de;
      #pragma unroll
      for (int m = 4; m <= 32; m <<= 1) { es += __shfl_xor(es, m); eq += __shfl_xor(eq, m); }
      if ((t & 63) == 0) ((double2*)(sm + OFF_EPZRP))[w] = make_double2(es, eq);
    }
    wg_barrier();  // B1

    // ---- Seg2: LN512 -> z / rh | EP LN128 -> ze / rhep ----
    {
      float S = 0.f, Q = 0.f;
      const float4* zp = (const float4*)(sm + OFF_ZRP);
      #pragma unroll
      for (int i = 0; i < 4; ++i) { const float4 v = zp[i]; S += v.x + v.z; Q += v.y + v.w; }
      const float mean = S * (1.f / 512.f);
      const float var = Q * (1.f / 512.f) - mean * mean;
      const float inv = 1.f / (sqrtf(var + 1e-5f) + 1e-5f);
      const float s2v = gz * ((d - mean) * inv) + bz;
      float sv = 0.2f * (s1zr_c + s2v) + 0.5f;
      sv = fminf(fmaxf(sv, 0.f), 1.f);
      if (t < 256) ((float*)(sm + OFF_Z))[t] = sv;
      else {
        const float rhv = sv * (fz * hf[t - 256]);
        ((_Float16*)(sm + OFF_RH))[t - 256] = (_Float16)rhv;
      }
    }
    if ((t & 3) == 0) {                 // EP-zr finish (128 threads)
      double S = 0.0, Q = 0.0;
      const double2* ep = (const double2*)(sm + OFF_EPZRP);
      #pragma unroll
      for (int i = 0; i < 8; ++i) { S += ep[i].x; Q += ep[i].y; }
      const double mean = S * (1.0 / 128.0);
      const double var = Q * (1.0 / 128.0) - mean * mean;
      const double den = sqrt(var + 1e-5) + 1e-5;
      const double s2e = (double)gse * ((de - mean) / den) + (double)bse;
      double se = 0.2 * (s1ezr_c + s2e) + 0.5;
      se = fmin(fmax(se, 0.0), 1.0);
      if (je < 64) ((double*)(sm + OFF_ZEE))[je] = se;
      else         ((double*)(sm + OFF_RHEP))[je - 64] = se * hepd[je - 64];
    }
    wg_barrier();  // B2

    // ---- Seg3: hh dot (t<256, conflict-free pages) | EP-hh dot (t>=256) ----
    float dh = 0.f;
    double deh = 0.0;
    if (t < 256) {
      const v8h* rhv8 = (const v8h*)(sm + OFF_RH);
      const v8h* uhv  = (const v8h*)(sm + OFF_UH);
      float c0 = 0.f, c1 = 0.f, c2 = 0.f, c3 = 0.f;
      #pragma unroll
      for (int p = 0; p < 32; ++p) {
        const v8h rc = rhv8[p];
        const v8h uc = uhv[p * 256 + t];
        c0 = fdot2_(pr<0>(rc), pr<0>(uc), c0);
        c1 = fdot2_(pr<1>(rc), pr<1>(uc), c1);
        c2 = fdot2_(pr<2>(rc), pr<2>(uc), c2);
        c3 = fdot2_(pr<3>(rc), pr<3>(uc), c3);
      }
      dh = (c0 + c1) + (c2 + c3);
      float s_ = dh, q_ = dh * dh;
      #pragma unroll
      for (int m = 1; m <= 32; m <<= 1) { s_ += __shfl_xor(s_, m); q_ += __shfl_xor(q_, m); }
      if ((t & 63) == 0) ((float2*)(sm + OFF_HHP))[w] = make_float2(s_, q_);
    } else {
      const double2* rp = (const double2*)((double*)(sm + OFF_RHEP) + 16 * qe);
      double acc = 0.0;
      #pragma unroll
      for (int i = 0; i < 8; ++i) {
        const double2 rv = rp[i];
        acc += rv.x * (double)ueh[2 * i] + rv.y * (double)ueh[2 * i + 1];
      }
      acc += __shfl_xor(acc, 1); acc += __shfl_xor(acc, 2);
      deh = acc;
      double es = deh, eq = deh * deh;
      #pragma unroll
      for (int m = 4; m <= 32; m <<= 1) { es += __shfl_xor(es, m); eq += __shfl_xor(eq, m); }
      if ((t & 63) == 0) ((double2*)(sm + OFF_EPHHP))[w - 4] = make_double2(es, eq);
    }
    wg_barrier();  // B3

    // ---- Seg4: main h update | EP hep update ----
    const int xm = maskl[tt];
    if (t < 256) {
      float S = 0.f, Q = 0.f;
      const float4* hp4 = (const float4*)(sm + OFF_HHP);
      #pragma unroll
      for (int i = 0; i < 2; ++i) { const float4 v = hp4[i]; S += v.x + v.z; Q += v.y + v.w; }
      const float mean = S * (1.f / 256.f);
      const float var = Q * (1.f / 256.f) - mean * mean;
      const float inv = 1.f / (sqrtf(var + 1e-5f) + 1e-5f);
      const float hhv = gh * ((dh - mean) * inv) + bh;
      const float z = ((float*)(sm + OFF_Z))[t];
      const float hzf = fz * hf[t];
      const float hn = z * hzf + (1.f - z) * tanhf(s1h_c + hhv);
      const float hc_ = (xm > 0) ? hn : hzf;
      hf[t] = hc_;
      const float ho = __shfl_xor(hc_, 1);
      if (!(t & 1)) {
        h2 p2; p2[0] = (_Float16)hc_; p2[1] = (_Float16)ho;
        ((h2*)(sm + OFF_H2))[t >> 1] = p2;
      }
    } else if ((t & 3) == 0) {          // EP finish (64 threads, col jeh)
      double S = 0.0, Q = 0.0;
      const double2* ep = (const double2*)(sm + OFF_EPHHP);
      #pragma unroll
      for (int i = 0; i < 4; ++i) { S += ep[i].x; Q += ep[i].y; }
      const double mean = S * (1.0 / 64.0);
      const double var = Q * (1.0 / 64.0) - mean * mean;
      const double den = sqrt(var + 1e-5) + 1e-5;
      const double hhe = (double)ghe * ((deh - mean) / den) + (double)bhe;
      const double ze = ((double*)(sm + OFF_ZEE))[jeh];
      const double hold = hepd[jeh];
      const double hepn = ze * hold + (1.0 - ze) * tanh(s1ehh_c + hhe);
      hepd[jeh] = (xm > 0) ? hepn : hold;
    }
    wg_barrier();  // B4

    s1zr_c = s1zr_n; s1h_c = s1h_n; s1ezr_c = s1ezr_n; s1ehh_c = s1ehh_n;
  }
  // final h write (step 2047)
  if (t < 256) out[((((size_t)b << 11) | 2047)) * 256 + t] = hf[t];
}

// ---------------------------------------------------------------------------
extern "C" void kernel_launch(void* const* d_in, const int* in_sizes, int n_in,
                              void* d_out, int out_size, void* d_ws, size_t ws_size,
                              hipStream_t stream)
{
  (void)in_sizes; (void)n_in; (void)out_size;
  const float* x       = (const float*)d_in[0];
  const int*   mask    = (const int*)d_in[1];
  const float* W       = (const float*)d_in[2];
  const float* U       = (const float*)d_in[3];
  const float* bvec    = (const float*)d_in[4];
  const float* gammas  = (const float*)d_in[5];
  const float* betas   = (const float*)d_in[6];
  const float* W_EP    = (const float*)d_in[7];
  const float* U_EP    = (const float*)d_in[8];
  const float* b_EP    = (const float*)d_in[9];
  const float* gammasE = (const float*)d_in[10];
  const float* betasE  = (const float*)d_in[11];
  const float* W1_EP   = (const float*)d_in[12];
  const float* b1_EP   = (const float*)d_in[13];
  float* out = (float*)d_out;

  const size_t NR = 131072;                 // B*T
  const size_t S1_SZ    = NR * 768 * 2;     // f16
  const size_t S1E64_SZ = NR * 192 * 8;     // f64
  const size_t S1E32_SZ = NR * 192 * 4;     // f32 fallback
  const size_t WSMALL = 262144 + 131072 + 393216 + 196608;
  const int s1e64 = (ws_size >= S1_SZ + S1E64_SZ + WSMALL) ? 1 : 0;
  const size_t S1E_SZ = s1e64 ? S1E64_SZ : S1E32_SZ;
  if (ws_size < S1_SZ + S1E32_SZ + WSMALL) return;  // cannot run

  char* ws = (char*)d_ws;
  size_t off = 0;
  void* s1e      = (void*)(ws + off);      off += S1E_SZ;
  _Float16* s1   = (_Float16*)(ws + off);  off += S1_SZ;
  _Float16* uzr  = (_Float16*)(ws + off);  off += 262144;
  _Float16* uh   = (_Float16*)(ws + off);  off += 131072;
  _Float16* wt   = (_Float16*)(ws + off);  off += 393216;
  float* wept    = (float*)(ws + off);     off += 196608;

  prep_kernel<<<dim3(1728), dim3(256), 0, stream>>>(
      W, U, W_EP, wt, uzr, uh, wept);
  ph1_main_kernel<<<dim3(8192), dim3(256), 0, stream>>>(
      x, wt, bvec, gammas, betas, s1);
  ph1_ep_kernel<<<dim3(8192), dim3(192), 0, stream>>>(
      x, wept, b_EP, gammasE, betasE, s1e, s1e64);

  hipFuncSetAttribute(reinterpret_cast<const void*>(scan_kernel),
                      hipFuncAttributeMaxDynamicSharedMemorySize, SCAN_LDS_BYTES);
  scan_kernel<<<dim3(64), dim3(512), SCAN_LDS_BYTES, stream>>>(
      uzr, uh, U_EP, s1, (const void*)s1e, s1e64, mask,
      gammas + 768, betas + 768, gammasE + 192, betasE + 192,
      W1_EP, b1_EP, out);
}